// Round 1
// baseline (343.207 us; speedup 1.0000x reference)
//
#include <hip/hip_runtime.h>
#include <math.h>

// GraphAttention: Q=4, N=50000, K=8, F_IN=128, F_OUT=64
// score[q,n] = mean_k( tanh( mean_j(q[e_j]) @ W1 + b1 )[e_k] ) @ W2 + b2
// Key identity: GEMM commutes with mean-gather, so:
//   y  = query @ W1                       (dense, no bias)
//   h  = tanh( mean_k y[e_k] + b1 )
//   s1 = h @ W2                           (scalar per node)
//   score = mean_k s1[e_k] + b2           (scalar gather!)
// Then softmax over N and context = sum_n w_n * values[n].

#define FIN 128
#define FOUT 64
#define KN 8

// ---------------- A: y[n,f] = sum_c x[n,c] * W1[c,f] ----------------
// 64 nodes per block, wave-per-node, W1 staged in LDS (32 KB).
__global__ void k_xw(const float* __restrict__ x, const float* __restrict__ W1,
                     float* __restrict__ y, int N) {
    __shared__ float Ws[FIN * FOUT];
    __shared__ float xs[4][FIN];
    const int tid = threadIdx.x;
    for (int i = tid; i < FIN * FOUT; i += 256) Ws[i] = W1[i];
    __syncthreads();
    const int wave = tid >> 6, lane = tid & 63;
    const int base = blockIdx.x * 64;
    for (int it = 0; it < 16; ++it) {
        const int n = base + it * 4 + wave;
        const bool valid = (n < N);
        if (valid) {
            xs[wave][lane]      = x[(size_t)n * FIN + lane];
            xs[wave][lane + 64] = x[(size_t)n * FIN + 64 + lane];
        }
        __syncthreads();
        if (valid) {
            float acc = 0.f;
            #pragma unroll
            for (int c = 0; c < FIN; ++c)
                acc += xs[wave][c] * Ws[c * FOUT + lane];
            y[(size_t)n * FOUT + lane] = acc;
        }
        __syncthreads();
    }
}

// ---------------- B: s1[n] = tanh(mean_k y[e_k] + b1) . W2 ----------------
// wave-per-node: lane = feature f in [0,64)
__global__ void k_agg(const float* __restrict__ y, const int* __restrict__ edges,
                      const float* __restrict__ b1, const float* __restrict__ W2,
                      float* __restrict__ s1, int N) {
    const int tid = threadIdx.x;
    const int wave = tid >> 6, lane = tid & 63;
    const int n = blockIdx.x * 4 + wave;
    if (n >= N) return;
    int e = 0;
    if (lane < KN) e = edges[n * KN + lane];
    float acc = 0.f;
    #pragma unroll
    for (int k = 0; k < KN; ++k) {
        const int ek = __shfl(e, k);
        acc += y[(size_t)ek * FOUT + lane];
    }
    const float h = tanhf(acc * 0.125f + b1[lane]);
    float p = h * W2[lane];
    #pragma unroll
    for (int off = 32; off; off >>= 1) p += __shfl_xor(p, off);
    if (lane == 0) s1[n] = p;
}

// ---------------- C: score[n] = mean_k s1[e_k] + b2 ----------------
__global__ void k_score(const float* __restrict__ s1, const int* __restrict__ edges,
                        const float* __restrict__ b2, float* __restrict__ score, int N) {
    const int n = blockIdx.x * blockDim.x + threadIdx.x;
    if (n >= N) return;
    float acc = 0.f;
    #pragma unroll
    for (int k = 0; k < KN; ++k) acc += s1[edges[n * KN + k]];
    score[n] = acc * 0.125f + b2[0];
}

// ---------------- D1: per-q softmax stats (max, 1/Z); zero context ----------------
__global__ __launch_bounds__(1024) void k_stats(const float* __restrict__ score,
                                                float* __restrict__ mz,
                                                float* __restrict__ ctx, int N) {
    const int q = blockIdx.x;
    const float* s = score + (size_t)q * N;
    __shared__ float red[16];
    __shared__ float mshared;
    const int tid = threadIdx.x;

    float m = -1e30f;
    for (int i = tid; i < N; i += 1024) m = fmaxf(m, s[i]);
    #pragma unroll
    for (int off = 32; off; off >>= 1) m = fmaxf(m, __shfl_xor(m, off));
    if ((tid & 63) == 0) red[tid >> 6] = m;
    __syncthreads();
    if (tid == 0) {
        float mm = red[0];
        for (int i = 1; i < 16; ++i) mm = fmaxf(mm, red[i]);
        mshared = mm;
    }
    __syncthreads();
    m = mshared;

    float z = 0.f;
    for (int i = tid; i < N; i += 1024) z += expf(s[i] - m);
    #pragma unroll
    for (int off = 32; off; off >>= 1) z += __shfl_xor(z, off);
    __syncthreads();   // all reads of red (max phase) done
    if ((tid & 63) == 0) red[tid >> 6] = z;
    __syncthreads();
    if (tid == 0) {
        float zz = 0.f;
        for (int i = 0; i < 16; ++i) zz += red[i];
        mz[q * 2]     = m;
        mz[q * 2 + 1] = 1.f / zz;
    }
    if (tid < FIN) ctx[q * FIN + tid] = 0.f;
}

// ---------------- D2: ctx[q,f] += sum_n w_n * values[q,n,f] ----------------
// 512 blocks per q; 256 threads = 2 groups of 128 (f = tid&127), 2 nodes in flight.
__global__ void k_context(const float* __restrict__ values, const float* __restrict__ score,
                          const float* __restrict__ mz, float* __restrict__ ctx, int N) {
    const int q  = blockIdx.x >> 9;
    const int cb = blockIdx.x & 511;
    const int tid = threadIdx.x;
    const int f = tid & 127;
    const int g = tid >> 7;
    const float m = mz[q * 2], invZ = mz[q * 2 + 1];
    const float* s = score + (size_t)q * N;
    const float* v = values + (size_t)q * N * FIN;
    const int chunk = (N + 511) >> 9;
    const int n0 = cb * chunk;
    const int n1 = min(n0 + chunk, N);
    float acc = 0.f;
    for (int n = n0 + g; n < n1; n += 2) {
        const float w = expf(s[n] - m) * invZ;
        acc += w * v[(size_t)n * FIN + f];
    }
    __shared__ float part[256];
    part[tid] = acc;
    __syncthreads();
    if (tid < 128) atomicAdd(&ctx[q * FIN + f], part[tid] + part[tid + 128]);
}

extern "C" void kernel_launch(void* const* d_in, const int* in_sizes, int n_in,
                              void* d_out, int out_size, void* d_ws, size_t ws_size,
                              hipStream_t stream) {
    const float* query  = (const float*)d_in[0];
    const float* values = (const float*)d_in[1];
    const int*   edges  = (const int*)d_in[2];
    const float* W1     = (const float*)d_in[3];
    const float* b1     = (const float*)d_in[4];
    const float* W2     = (const float*)d_in[5];
    const float* b2     = (const float*)d_in[6];

    const int N = in_sizes[2] / KN;                 // 50000
    const int Q = in_sizes[0] / (N * FIN);          // 4

    float* out   = (float*)d_out;
    float* ctx   = out;                             // [Q,128]
    float* score = out + (size_t)Q * FIN;           // [Q,N]

    float* y  = (float*)d_ws;                       // [N,64]
    float* s1 = y + (size_t)N * FOUT;               // [N]
    float* mz = s1 + N;                             // [Q,2]

    for (int q = 0; q < Q; ++q) {
        k_xw   <<<(N + 63) / 64,  256, 0, stream>>>(query + (size_t)q * N * FIN, W1, y, N);
        k_agg  <<<(N + 3) / 4,    256, 0, stream>>>(y, edges, b1, W2, s1, N);
        k_score<<<(N + 255) / 256,256, 0, stream>>>(s1, edges, b2, score + (size_t)q * N, N);
    }
    k_stats  <<<Q,       1024, 0, stream>>>(score, mz, ctx, N);
    k_context<<<Q * 512,  256, 0, stream>>>(values, score, mz, ctx, N);
}

// Round 2
// 183.607 us; speedup vs baseline: 1.8692x; 1.8692x over previous
//
#include <hip/hip_runtime.h>
#include <hip/hip_fp16.h>
#include <math.h>

// GraphAttention: Q=4, N=50000, K=8, F_IN=128, F_OUT=64
//   y  = query @ W1          (MFMA split-bf16, f16 output)   [Q,N,64]
//   s1 = tanh(mean_k y[e]+b1) . W2                           [Q,N]
//   score = mean_k s1[e] + b2                                [Q,N]
//   softmax over N; ctx = sum_n w_n * values[n]              [Q,128]

#define FIN 128
#define FOUT 64
#define KN 8

typedef short bf16x8 __attribute__((ext_vector_type(8)));
typedef float f32x4 __attribute__((ext_vector_type(4)));

__device__ inline short f2bf(float x) {
    unsigned u = __float_as_uint(x);
    unsigned r = (u + 0x7fffu + ((u >> 16) & 1u)) >> 16;
    return (short)r;
}
__device__ inline float bf2f(short s) {
    return __uint_as_float(((unsigned)(unsigned short)s) << 16);
}

// ---------------- Stage 1: y = query @ W1 (split-bf16 MFMA, f16 out) ----------------
// Block: 256 thr = 4 waves; each wave does 4 tiles of 16 nodes x 64 f.
// mfma_f32_16x16x32_bf16: A lane l -> A[row=l&15][k=(l>>4)*8+j]; C: col=l&15,row=(l>>4)*4+reg.
__global__ __launch_bounds__(256) void k_xw(const float* __restrict__ query,
                                            const float* __restrict__ W1,
                                            __half* __restrict__ y, int N) {
    __shared__ float Ws[FIN * FOUT];
    const int tid = threadIdx.x;
    for (int i = tid; i < FIN * FOUT; i += 256) Ws[i] = W1[i];
    __syncthreads();
    const int wave = tid >> 6, lane = tid & 63;
    const int lg = lane >> 4, lr = lane & 15;
    const int q = blockIdx.y;
    const int blockBase = blockIdx.x * 256;
    const float* qb = query + (size_t)q * N * FIN;
    __half* yq = y + (size_t)q * N * FOUT;

    f32x4 acc[4][4];
    #pragma unroll
    for (int t = 0; t < 4; ++t)
        #pragma unroll
        for (int nt = 0; nt < 4; ++nt) acc[t][nt] = (f32x4)0.f;

    for (int kk = 0; kk < 4; ++kk) {
        bf16x8 Bhi[4], Blo[4];
        #pragma unroll
        for (int nt = 0; nt < 4; ++nt)
            #pragma unroll
            for (int j = 0; j < 8; ++j) {
                int k = kk * 32 + lg * 8 + j;
                float w = Ws[k * FOUT + nt * 16 + lr];
                short h = f2bf(w);
                Bhi[nt][j] = h;
                Blo[nt][j] = f2bf(w - bf2f(h));
            }
        #pragma unroll
        for (int t = 0; t < 4; ++t) {
            int node = blockBase + wave * 64 + t * 16 + lr;
            int nc = node < N ? node : N - 1;
            const float4* ap = (const float4*)(qb + (size_t)nc * FIN + kk * 32 + lg * 8);
            float4 x0 = ap[0], x1 = ap[1];
            float xs[8] = {x0.x, x0.y, x0.z, x0.w, x1.x, x1.y, x1.z, x1.w};
            bf16x8 Ahi, Alo;
            #pragma unroll
            for (int j = 0; j < 8; ++j) {
                short h = f2bf(xs[j]);
                Ahi[j] = h;
                Alo[j] = f2bf(xs[j] - bf2f(h));
            }
            #pragma unroll
            for (int nt = 0; nt < 4; ++nt) {
                acc[t][nt] = __builtin_amdgcn_mfma_f32_16x16x32_bf16(Ahi, Bhi[nt], acc[t][nt], 0, 0, 0);
                acc[t][nt] = __builtin_amdgcn_mfma_f32_16x16x32_bf16(Alo, Bhi[nt], acc[t][nt], 0, 0, 0);
                acc[t][nt] = __builtin_amdgcn_mfma_f32_16x16x32_bf16(Ahi, Blo[nt], acc[t][nt], 0, 0, 0);
            }
        }
    }
    #pragma unroll
    for (int t = 0; t < 4; ++t)
        #pragma unroll
        for (int r = 0; r < 4; ++r) {
            int node = blockBase + wave * 64 + t * 16 + lg * 4 + r;
            if (node < N) {
                #pragma unroll
                for (int nt = 0; nt < 4; ++nt)
                    yq[(size_t)node * FOUT + nt * 16 + lr] = __float2half(acc[t][nt][r]);
            }
        }
}

// ---------------- Stage 2: s1 = tanh(mean_k y[e]+b1).W2, wave-per-node ----------------
__global__ __launch_bounds__(256) void k_agg(const __half* __restrict__ y,
                                             const int* __restrict__ edges,
                                             const float* __restrict__ b1,
                                             const float* __restrict__ W2,
                                             float* __restrict__ s1, int N) {
    const int tid = threadIdx.x;
    const int wave = tid >> 6, lane = tid & 63;
    const int n = blockIdx.x * 4 + wave;
    const int q = blockIdx.y;
    if (n >= N) return;
    const __half* yq = y + (size_t)q * N * FOUT;
    int e = 0;
    if (lane < KN) e = edges[n * KN + lane];
    float acc = 0.f;
    #pragma unroll
    for (int k = 0; k < KN; ++k) {
        int ek = __shfl(e, k);
        acc += __half2float(yq[(size_t)ek * FOUT + lane]);
    }
    float h = tanhf(acc * 0.125f + b1[lane]);
    float p = h * W2[lane];
    #pragma unroll
    for (int off = 32; off; off >>= 1) p += __shfl_xor(p, off);
    if (lane == 0) s1[(size_t)q * N + n] = p;
}

// ---------------- Stage 3: score = mean_k s1[e] + b2 ----------------
__global__ void k_score(const float* __restrict__ s1, const int* __restrict__ edges,
                        const float* __restrict__ b2, float* __restrict__ score, int N) {
    const int n = blockIdx.x * 256 + threadIdx.x;
    const int q = blockIdx.y;
    if (n >= N) return;
    const float* s1q = s1 + (size_t)q * N;
    float acc = 0.f;
    #pragma unroll
    for (int k = 0; k < KN; ++k) acc += s1q[edges[n * KN + k]];
    score[(size_t)q * N + n] = acc * 0.125f + b2[0];
}

// ---------------- Stage 4: softmax stats (max, 1/Z) + zero ctx ----------------
__global__ __launch_bounds__(1024) void k_stats(const float* __restrict__ score,
                                                float* __restrict__ mz,
                                                float* __restrict__ ctx, int N) {
    const int q = blockIdx.x;
    const float* s = score + (size_t)q * N;
    __shared__ float red[16];
    __shared__ float mshared;
    const int tid = threadIdx.x;

    float m = -1e30f;
    for (int i = tid; i < N; i += 1024) m = fmaxf(m, s[i]);
    #pragma unroll
    for (int off = 32; off; off >>= 1) m = fmaxf(m, __shfl_xor(m, off));
    if ((tid & 63) == 0) red[tid >> 6] = m;
    __syncthreads();
    if (tid == 0) {
        float mm = red[0];
        for (int i = 1; i < 16; ++i) mm = fmaxf(mm, red[i]);
        mshared = mm;
    }
    __syncthreads();
    m = mshared;

    float z = 0.f;
    for (int i = tid; i < N; i += 1024) z += expf(s[i] - m);
    #pragma unroll
    for (int off = 32; off; off >>= 1) z += __shfl_xor(z, off);
    __syncthreads();
    if ((tid & 63) == 0) red[tid >> 6] = z;
    __syncthreads();
    if (tid == 0) {
        float zz = 0.f;
        for (int i = 0; i < 16; ++i) zz += red[i];
        mz[q * 2] = m;
        mz[q * 2 + 1] = 1.f / zz;
    }
    if (tid < FIN) ctx[q * FIN + tid] = 0.f;
}

// ---------------- Stage 5: ctx += sum_n w_n * values[n] (float4/lane) ----------------
__global__ __launch_bounds__(256) void k_context(const float* __restrict__ values,
                                                 const float* __restrict__ score,
                                                 const float* __restrict__ mz,
                                                 float* __restrict__ ctx, int N) {
    const int q = blockIdx.x >> 9;
    const int cb = blockIdx.x & 511;
    const int tid = threadIdx.x;
    const int fi = tid & 31, g = tid >> 5;   // 8 node-groups x 32 lanes (16B each)
    const float m = mz[2 * q], invZ = mz[2 * q + 1];
    const float* s = score + (size_t)q * N;
    const float4* v = (const float4*)(values + (size_t)q * N * FIN);
    const int chunk = (N + 511) >> 9;
    const int n0 = cb * chunk, n1 = min(n0 + chunk, N);
    float4 acc = make_float4(0.f, 0.f, 0.f, 0.f);
    for (int n = n0 + g; n < n1; n += 8) {
        const float w = expf(s[n] - m) * invZ;
        float4 vv = v[(size_t)n * 32 + fi];
        acc.x += w * vv.x; acc.y += w * vv.y; acc.z += w * vv.z; acc.w += w * vv.w;
    }
    __shared__ float4 part[256];
    part[tid] = acc;
    __syncthreads();
    if (tid < 32) {
        float4 a = part[tid];
        #pragma unroll
        for (int gg = 1; gg < 8; ++gg) {
            float4 b = part[gg * 32 + tid];
            a.x += b.x; a.y += b.y; a.z += b.z; a.w += b.w;
        }
        atomicAdd(&ctx[q * FIN + fi * 4 + 0], a.x);
        atomicAdd(&ctx[q * FIN + fi * 4 + 1], a.y);
        atomicAdd(&ctx[q * FIN + fi * 4 + 2], a.z);
        atomicAdd(&ctx[q * FIN + fi * 4 + 3], a.w);
    }
}

extern "C" void kernel_launch(void* const* d_in, const int* in_sizes, int n_in,
                              void* d_out, int out_size, void* d_ws, size_t ws_size,
                              hipStream_t stream) {
    const float* query  = (const float*)d_in[0];
    const float* values = (const float*)d_in[1];
    const int*   edges  = (const int*)d_in[2];
    const float* W1     = (const float*)d_in[3];
    const float* b1     = (const float*)d_in[4];
    const float* W2     = (const float*)d_in[5];
    const float* b2     = (const float*)d_in[6];

    const int N = in_sizes[2] / KN;           // 50000
    const int Q = in_sizes[0] / (N * FIN);    // 4

    float* out   = (float*)d_out;
    float* ctx   = out;                       // [Q,128]
    float* score = out + (size_t)Q * FIN;     // [Q,N]

    __half* y = (__half*)d_ws;                                          // [Q,N,64] f16
    float* s1 = (float*)((char*)d_ws + (size_t)Q * N * FOUT * sizeof(__half)); // [Q,N]
    float* mz = s1 + (size_t)Q * N;                                     // [Q,2]

    dim3 g1((N + 255) / 256, Q);
    k_xw<<<g1, 256, 0, stream>>>(query, W1, y, N);
    dim3 g2((N + 3) / 4, Q);
    k_agg<<<g2, 256, 0, stream>>>(y, edges, b1, W2, s1, N);
    dim3 g3((N + 255) / 256, Q);
    k_score<<<g3, 256, 0, stream>>>(s1, edges, b2, score, N);
    k_stats<<<Q, 1024, 0, stream>>>(score, mz, ctx, N);
    k_context<<<Q * 512, 256, 0, stream>>>(values, score, mz, ctx, N);
}

// Round 3
// 129.055 us; speedup vs baseline: 2.6594x; 1.4227x over previous
//
#include <hip/hip_runtime.h>
#include <hip/hip_fp16.h>
#include <math.h>

// GraphAttention: Q=4, N=50000, K=8, F_IN=128, F_OUT=64
//   y  = query @ W1          (MFMA split-bf16, f16 output)   [Q,N,64]
//   s1 = tanh(mean_k y[e]+b1) . W2                           [Q,N]
//   score = mean_k s1[e] + b2                                [Q,N]
//   softmax WITHOUT max-sub (scores bounded ~|2|): w=exp(s)/Z
//   ctx = (sum_n exp(s_n) * values[n]) / Z                   [Q,128]

#define FIN 128
#define FOUT 64
#define KN 8

typedef short bf16x8 __attribute__((ext_vector_type(8)));
typedef float f32x4 __attribute__((ext_vector_type(4)));

__device__ inline short f2bf(float x) {
    unsigned u = __float_as_uint(x);
    unsigned r = (u + 0x7fffu + ((u >> 16) & 1u)) >> 16;
    return (short)r;
}
__device__ inline float bf2f(short s) {
    return __uint_as_float(((unsigned)(unsigned short)s) << 16);
}

// ---------------- Stage 0: pack W1 into MFMA B-fragment order (hi/lo bf16);
// zero Z and ctx. One block of 512 threads.
__global__ __launch_bounds__(512) void k_prep(const float* __restrict__ W1,
                                              short* __restrict__ W1pk,
                                              float* __restrict__ Z,
                                              float* __restrict__ ctx, int Q) {
    const int tid = threadIdx.x;
    // pairs p = f*64 + lane, f in [0,16), lane in [0,64)
    for (int it = 0; it < 2; ++it) {
        int p = tid + it * 512;
        int f = p >> 6, lane = p & 63;
        int kk = f >> 2, nt = f & 3;
        int lg = lane >> 4, lr = lane & 15;
        #pragma unroll
        for (int j = 0; j < 8; ++j) {
            float w = W1[(kk * 32 + lg * 8 + j) * FOUT + nt * 16 + lr];
            short h = f2bf(w);
            W1pk[(size_t)p * 8 + j] = h;                      // hi bank
            W1pk[1024 * 8 + (size_t)p * 8 + j] = f2bf(w - bf2f(h)); // lo bank
        }
    }
    if (tid < Q * FIN) ctx[tid] = 0.f;
    if (tid < Q) Z[tid] = 0.f;
}

// ---------------- Stage 1: y = query @ W1 (split-bf16 MFMA, f16 out) ----------------
// 256 thr = 4 waves; block covers 256 nodes. B-frags loaded from packed global (L2-hot).
__global__ __launch_bounds__(256) void k_xw(const float* __restrict__ query,
                                            const short* __restrict__ W1pk,
                                            __half* __restrict__ y, int N) {
    const int tid = threadIdx.x;
    const int wave = tid >> 6, lane = tid & 63;
    const int lg = lane >> 4, lr = lane & 15;
    const int q = blockIdx.y;
    const int blockBase = blockIdx.x * 256;
    const float* qb = query + (size_t)q * N * FIN;
    __half* yq = y + (size_t)q * N * FOUT;
    const bf16x8* Bp = (const bf16x8*)W1pk;   // [2][16][64] frags

    f32x4 acc[4][4];
    #pragma unroll
    for (int t = 0; t < 4; ++t)
        #pragma unroll
        for (int nt = 0; nt < 4; ++nt) acc[t][nt] = (f32x4)0.f;

    for (int kk = 0; kk < 4; ++kk) {
        bf16x8 Bhi[4], Blo[4];
        #pragma unroll
        for (int nt = 0; nt < 4; ++nt) {
            Bhi[nt] = Bp[(kk * 4 + nt) * 64 + lane];
            Blo[nt] = Bp[1024 + (kk * 4 + nt) * 64 + lane];
        }
        #pragma unroll
        for (int t = 0; t < 4; ++t) {
            int node = blockBase + wave * 64 + t * 16 + lr;
            int nc = node < N ? node : N - 1;
            const float4* ap = (const float4*)(qb + (size_t)nc * FIN + kk * 32 + lg * 8);
            float4 x0 = ap[0], x1 = ap[1];
            float xs[8] = {x0.x, x0.y, x0.z, x0.w, x1.x, x1.y, x1.z, x1.w};
            bf16x8 Ahi, Alo;
            #pragma unroll
            for (int j = 0; j < 8; ++j) {
                short h = f2bf(xs[j]);
                Ahi[j] = h;
                Alo[j] = f2bf(xs[j] - bf2f(h));
            }
            #pragma unroll
            for (int nt = 0; nt < 4; ++nt) {
                acc[t][nt] = __builtin_amdgcn_mfma_f32_16x16x32_bf16(Ahi, Bhi[nt], acc[t][nt], 0, 0, 0);
                acc[t][nt] = __builtin_amdgcn_mfma_f32_16x16x32_bf16(Alo, Bhi[nt], acc[t][nt], 0, 0, 0);
                acc[t][nt] = __builtin_amdgcn_mfma_f32_16x16x32_bf16(Ahi, Blo[nt], acc[t][nt], 0, 0, 0);
            }
        }
    }
    #pragma unroll
    for (int t = 0; t < 4; ++t)
        #pragma unroll
        for (int r = 0; r < 4; ++r) {
            int node = blockBase + wave * 64 + t * 16 + lg * 4 + r;
            if (node < N) {
                #pragma unroll
                for (int nt = 0; nt < 4; ++nt)
                    yq[(size_t)node * FOUT + nt * 16 + lr] = __float2half(acc[t][nt][r]);
            }
        }
}

// ---------------- Stage 2: s1 = tanh(mean_k y[e]+b1).W2, 2 nodes/wave, half2 loads ----------------
__global__ __launch_bounds__(256) void k_agg(const __half* __restrict__ y,
                                             const int* __restrict__ edges,
                                             const float* __restrict__ b1,
                                             const float* __restrict__ W2,
                                             float* __restrict__ s1, int N) {
    const int tid = threadIdx.x;
    const int wave = tid >> 6, lane = tid & 63;
    const int half = lane >> 5, fl = lane & 31;   // fl = feature-pair index
    const int q = blockIdx.y;
    int n = (blockIdx.x * 4 + wave) * 2 + half;
    if (n >= N) n = N - 1;
    const __half* yq = y + (size_t)q * N * FOUT;
    int e = 0;
    if (fl < KN) e = edges[n * KN + fl];
    float ax = 0.f, ay = 0.f;
    #pragma unroll
    for (int k = 0; k < KN; ++k) {
        int ek = __shfl(e, half * 32 + k);
        __half2 v = *(const __half2*)(yq + (size_t)ek * FOUT + fl * 2);
        float2 vf = __half22float2(v);
        ax += vf.x; ay += vf.y;
    }
    float2 bv = *(const float2*)(b1 + fl * 2);
    float2 wv = *(const float2*)(W2 + fl * 2);
    float h0 = tanhf(ax * 0.125f + bv.x);
    float h1 = tanhf(ay * 0.125f + bv.y);
    float p = h0 * wv.x + h1 * wv.y;
    #pragma unroll
    for (int off = 16; off; off >>= 1) p += __shfl_xor(p, off);
    if (fl == 0) s1[(size_t)q * N + n] = p;
}

// ---------------- Stage 3: score = mean_k s1[e]+b2; w_un = exp(score); Z += Σ ----------------
__global__ __launch_bounds__(256) void k_score(const float* __restrict__ s1,
                                               const int* __restrict__ edges,
                                               const float* __restrict__ b2,
                                               float* __restrict__ score,
                                               float* __restrict__ wun,
                                               float* __restrict__ Z, int N) {
    const int n = blockIdx.x * 256 + threadIdx.x;
    const int q = blockIdx.y;
    const float* s1q = s1 + (size_t)q * N;
    float ex = 0.f;
    if (n < N) {
        float acc = 0.f;
        #pragma unroll
        for (int k = 0; k < KN; ++k) acc += s1q[edges[n * KN + k]];
        float sc = acc * 0.125f + b2[0];
        score[(size_t)q * N + n] = sc;
        ex = expf(sc);
        wun[(size_t)q * N + n] = ex;
    }
    float p = ex;
    #pragma unroll
    for (int off = 32; off; off >>= 1) p += __shfl_xor(p, off);
    __shared__ float red[4];
    if ((threadIdx.x & 63) == 0) red[threadIdx.x >> 6] = p;
    __syncthreads();
    if (threadIdx.x == 0) atomicAdd(&Z[q], red[0] + red[1] + red[2] + red[3]);
}

// ---------------- Stage 4: ctx_un = sum_n w_un[n] * values[n] (unroll-4 float4) ----------------
__global__ __launch_bounds__(256) void k_context(const float* __restrict__ values,
                                                 const float* __restrict__ wun,
                                                 float* __restrict__ ctx, int N) {
    const int q = blockIdx.y, cb = blockIdx.x;   // 256 blocks per q
    const int tid = threadIdx.x;
    const int fi = tid & 31, g = tid >> 5;       // 8 node-groups x 32 float4-cols
    const float4* v = (const float4*)(values + (size_t)q * N * FIN);
    const float* w = wun + (size_t)q * N;
    const int chunk = (N + 255) >> 8;
    const int n0 = cb * chunk, n1 = min(n0 + chunk, N);
    float4 acc = make_float4(0.f, 0.f, 0.f, 0.f);
    int n = n0 + g;
    for (; n + 24 < n1; n += 32) {
        float w0 = w[n], w1 = w[n + 8], w2 = w[n + 16], w3 = w[n + 24];
        float4 a = v[(size_t)n * 32 + fi];
        float4 b = v[(size_t)(n + 8) * 32 + fi];
        float4 c = v[(size_t)(n + 16) * 32 + fi];
        float4 d = v[(size_t)(n + 24) * 32 + fi];
        acc.x = fmaf(w0, a.x, fmaf(w1, b.x, fmaf(w2, c.x, fmaf(w3, d.x, acc.x))));
        acc.y = fmaf(w0, a.y, fmaf(w1, b.y, fmaf(w2, c.y, fmaf(w3, d.y, acc.y))));
        acc.z = fmaf(w0, a.z, fmaf(w1, b.z, fmaf(w2, c.z, fmaf(w3, d.z, acc.z))));
        acc.w = fmaf(w0, a.w, fmaf(w1, b.w, fmaf(w2, c.w, fmaf(w3, d.w, acc.w))));
    }
    for (; n < n1; n += 8) {
        float ww = w[n];
        float4 a = v[(size_t)n * 32 + fi];
        acc.x = fmaf(ww, a.x, acc.x);
        acc.y = fmaf(ww, a.y, acc.y);
        acc.z = fmaf(ww, a.z, acc.z);
        acc.w = fmaf(ww, a.w, acc.w);
    }
    __shared__ float4 part[256];
    part[tid] = acc;
    __syncthreads();
    if (tid < 32) {
        float4 a = part[tid];
        #pragma unroll
        for (int gg = 1; gg < 8; ++gg) {
            float4 b = part[gg * 32 + tid];
            a.x += b.x; a.y += b.y; a.z += b.z; a.w += b.w;
        }
        atomicAdd(&ctx[q * FIN + fi * 4 + 0], a.x);
        atomicAdd(&ctx[q * FIN + fi * 4 + 1], a.y);
        atomicAdd(&ctx[q * FIN + fi * 4 + 2], a.z);
        atomicAdd(&ctx[q * FIN + fi * 4 + 3], a.w);
    }
}

// ---------------- Stage 5: ctx /= Z ----------------
__global__ void k_norm(float* __restrict__ ctx, const float* __restrict__ Z) {
    const int q = blockIdx.x;
    ctx[q * FIN + threadIdx.x] *= (1.f / Z[q]);
}

extern "C" void kernel_launch(void* const* d_in, const int* in_sizes, int n_in,
                              void* d_out, int out_size, void* d_ws, size_t ws_size,
                              hipStream_t stream) {
    const float* query  = (const float*)d_in[0];
    const float* values = (const float*)d_in[1];
    const int*   edges  = (const int*)d_in[2];
    const float* W1     = (const float*)d_in[3];
    const float* b1     = (const float*)d_in[4];
    const float* W2     = (const float*)d_in[5];
    const float* b2     = (const float*)d_in[6];

    const int N = in_sizes[2] / KN;           // 50000
    const int Q = in_sizes[0] / (N * FIN);    // 4

    float* out   = (float*)d_out;
    float* ctx   = out;                       // [Q,128]
    float* score = out + (size_t)Q * FIN;     // [Q,N]

    char* ws = (char*)d_ws;
    __half* y  = (__half*)ws;                                   // [Q,N,64] f16
    size_t off = (size_t)Q * N * FOUT * sizeof(__half);
    float* s1  = (float*)(ws + off);  off += (size_t)Q * N * sizeof(float);   // [Q,N]
    float* wun = (float*)(ws + off);  off += (size_t)Q * N * sizeof(float);   // [Q,N]
    short* W1pk = (short*)(ws + off); off += (size_t)2 * 16 * 64 * 8 * sizeof(short);
    float* Z   = (float*)(ws + off);                            // [Q]

    k_prep<<<1, 512, 0, stream>>>(W1, W1pk, Z, ctx, Q);
    dim3 g1((N + 255) / 256, Q);
    k_xw<<<g1, 256, 0, stream>>>(query, W1pk, y, N);
    dim3 g2((N + 7) / 8, Q);
    k_agg<<<g2, 256, 0, stream>>>(y, edges, b1, W2, s1, N);
    dim3 g3((N + 255) / 256, Q);
    k_score<<<g3, 256, 0, stream>>>(s1, edges, b2, score, wun, Z, N);
    dim3 g4(256, Q);
    k_context<<<g4, 256, 0, stream>>>(values, wun, ctx, N);
    k_norm<<<Q, FIN, 0, stream>>>(ctx, Z);
}